// Round 3
// baseline (923.759 us; speedup 1.0000x reference)
//
#include <hip/hip_runtime.h>
#include <cstdint>
#include <cstddef>

// Problem constants (B=1, S=65536, D=1024, P=512, E=3, C=2)
#define T_TOK 65536
#define DDIM  1024
#define PDIM  512

typedef __attribute__((ext_vector_type(8))) short          shortx8;
typedef __attribute__((ext_vector_type(8))) unsigned short ushortx8;
typedef __attribute__((ext_vector_type(4))) float          floatx4;

__device__ __forceinline__ unsigned short f2bf_rn(float x){
  unsigned int u = __float_as_uint(x);
  unsigned int r = u + 0x7FFFu + ((u >> 16) & 1u);
  return (unsigned short)(r >> 16);
}
__device__ __forceinline__ float bf2f(unsigned short h){
  return __uint_as_float(((unsigned int)h) << 16);
}
// fast tanh, NaN-safe
__device__ __forceinline__ float ftanh(float x){
  float ez = __expf(2.f * x);
  return 1.f - 2.f / (ez + 1.f);
}
// Swizzled LDS tile [128 rows][32 k elements] bf16, row stride 64 B.
// 16B block q (0..3) stored at q ^ ((row>>1)&3) -> all b128 ops 2-way (free).
__device__ __forceinline__ int lds_off(int row, int q){
  return row * 32 + ((q ^ ((row >> 1) & 3)) << 3);
}
__device__ __forceinline__ void split8(const float4& a, const float4& b,
                                       ushortx8& h, ushortx8& l){
  float x[8] = {a.x, a.y, a.z, a.w, b.x, b.y, b.z, b.w};
  #pragma unroll
  for (int i = 0; i < 8; i++){
    unsigned int u = __float_as_uint(x[i]);
    float r = x[i] - __uint_as_float(u & 0xFFFF0000u);   // exact residual
    h[i] = (unsigned short)(u >> 16);
    l[i] = (unsigned short)(__float_as_uint(r) >> 16);
  }
}

// ---------------------------------------------------------------------------
// prep: zero [glog 393216 | hist 12288 | h2 6144 | params 64 | bagsum 512 |
//             aggsum 512 | mf 1024] = 413760 ints; split-transpose W_t1 to
// bf16 hi/lo; transpose W_a1 to bf16 (rounded, hi only).
// ---------------------------------------------------------------------------
__global__ void prep(const float* __restrict__ Wt1, const float* __restrict__ Wa1,
                     unsigned short* __restrict__ W1th, unsigned short* __restrict__ W1tl,
                     unsigned short* __restrict__ Wath, int* __restrict__ zbase)
{
  int gid = blockIdx.x * 256 + threadIdx.x;
  if (gid < 413760){ zbase[gid] = 0; return; }
  int i = gid - 413760;
  if (i < 524288){
    int p = i >> 10, k = i & 1023;
    float x = Wt1[(size_t)k * PDIM + p];
    unsigned short h = f2bf_rn(x);
    W1th[i] = h;
    W1tl[i] = f2bf_rn(x - bf2f(h));
    return;
  }
  i -= 524288;
  if (i < 262144){
    int n = i >> 9, k = i & 511;
    Wath[i] = f2bf_rn(Wa1[(size_t)k * PDIM + n]);
  }
}

// ---------------------------------------------------------------------------
// gemm_main: patches = tanh(X @ W_t1), split-bf16 3-product (~fp32 accurate).
// 128x128 tile, BK=32, 256 threads. Epilogue: bf16 patch store, bag column
// sums (fp32 tanh values), fused gate GEMV partials -> atomicAdd glog[t][6].
// ---------------------------------------------------------------------------
__global__ __launch_bounds__(256, 4)
void gemm_main(const float* __restrict__ A,
               const unsigned short* __restrict__ Bhg,
               const unsigned short* __restrict__ Blg,
               unsigned short* __restrict__ Ptch,
               float* __restrict__ bagsum,
               float* __restrict__ glog,
               const float* __restrict__ Wg0,
               const float* __restrict__ Wg1,
               const float* __restrict__ Wg2)
{
  __shared__ __align__(16) unsigned short Ah[4096];
  __shared__ __align__(16) unsigned short Al[4096];
  __shared__ __align__(16) unsigned short Bh[4096];
  __shared__ __align__(16) unsigned short Bl[4096];

  const int tid = threadIdx.x;
  const int m0 = blockIdx.y * 128;
  const int n0 = blockIdx.x * 128;

  const int lane = tid & 63;
  const int wv   = tid >> 6;
  const int wm   = (wv & 1) << 6;
  const int wn   = (wv >> 1) << 6;
  const int lr   = lane & 15;
  const int quad = lane >> 4;

  const int arow = tid >> 1;
  const int akh  = (tid & 1) << 4;
  const int aq0  = (tid & 1) << 1;
  const float* asrc = A + (size_t)(m0 + arow) * DDIM + akh;

  floatx4 acc[4][4];
  #pragma unroll
  for (int i = 0; i < 4; i++)
    #pragma unroll
    for (int j = 0; j < 4; j++)
      acc[i][j] = (floatx4){0.f, 0.f, 0.f, 0.f};

  for (int kb = 0; kb < 32; ++kb){
    const int k0 = kb << 5;
    // stage A: 16 consecutive fp32 -> hi/lo bf16 (truncation split)
    {
      float4 v0 = *(const float4*)(asrc + k0);
      float4 v1 = *(const float4*)(asrc + k0 + 4);
      float4 v2 = *(const float4*)(asrc + k0 + 8);
      float4 v3 = *(const float4*)(asrc + k0 + 12);
      ushortx8 h0, l0, h1, l1;
      split8(v0, v1, h0, l0);
      split8(v2, v3, h1, l1);
      *(ushortx8*)&Ah[lds_off(arow, aq0)]     = h0;
      *(ushortx8*)&Ah[lds_off(arow, aq0 + 1)] = h1;
      *(ushortx8*)&Al[lds_off(arow, aq0)]     = l0;
      *(ushortx8*)&Al[lds_off(arow, aq0 + 1)] = l1;
    }
    // stage B (pre-split bf16 [n][k])
    #pragma unroll
    for (int it = 0; it < 2; it++){
      int lin = it * 256 + tid;
      int row = lin >> 2;
      int qb  = lin & 3;
      size_t off = (size_t)(n0 + row) * DDIM + k0 + qb * 8;
      ushortx8 bh = *(const ushortx8*)(Bhg + off);
      ushortx8 bl = *(const ushortx8*)(Blg + off);
      int d = lds_off(row, qb);
      *(ushortx8*)&Bh[d] = bh;
      *(ushortx8*)&Bl[d] = bl;
    }
    __syncthreads();
    shortx8 a0[4], a1[4], b0[4], b1[4];
    #pragma unroll
    for (int i = 0; i < 4; i++){
      a0[i] = *(const shortx8*)&Ah[lds_off(wm + i * 16 + lr, quad)];
      a1[i] = *(const shortx8*)&Al[lds_off(wm + i * 16 + lr, quad)];
      b0[i] = *(const shortx8*)&Bh[lds_off(wn + i * 16 + lr, quad)];
      b1[i] = *(const shortx8*)&Bl[lds_off(wn + i * 16 + lr, quad)];
    }
    #pragma unroll
    for (int i = 0; i < 4; i++){
      #pragma unroll
      for (int j = 0; j < 4; j++){
        acc[i][j] = __builtin_amdgcn_mfma_f32_16x16x32_bf16(a0[i], b0[j], acc[i][j], 0, 0, 0);
        acc[i][j] = __builtin_amdgcn_mfma_f32_16x16x32_bf16(a1[i], b0[j], acc[i][j], 0, 0, 0);
        acc[i][j] = __builtin_amdgcn_mfma_f32_16x16x32_bf16(a0[i], b1[j], acc[i][j], 0, 0, 0);
      }
    }
    __syncthreads();
  }

  // gate weights for this lane's 4 columns (L1-cached scalar loads)
  float wgr[4][6];
  #pragma unroll
  for (int j = 0; j < 4; j++){
    int c = n0 + wn + j * 16 + lr;
    wgr[j][0] = Wg0[c * 2]; wgr[j][1] = Wg0[c * 2 + 1];
    wgr[j][2] = Wg1[c * 2]; wgr[j][3] = Wg1[c * 2 + 1];
    wgr[j][4] = Wg2[c * 2]; wgr[j][5] = Wg2[c * 2 + 1];
  }

  float csum[4] = {0.f, 0.f, 0.f, 0.f};
  #pragma unroll
  for (int i = 0; i < 4; i++){
    float gp[4][6];
    #pragma unroll
    for (int k = 0; k < 4; k++)
      #pragma unroll
      for (int g = 0; g < 6; g++) gp[k][g] = 0.f;
    const int row = m0 + wm + i * 16 + quad * 4;
    #pragma unroll
    for (int j = 0; j < 4; j++){
      float t0 = ftanh(acc[i][j][0]);
      float t1 = ftanh(acc[i][j][1]);
      float t2 = ftanh(acc[i][j][2]);
      float t3 = ftanh(acc[i][j][3]);
      const int col = n0 + wn + j * 16 + lr;
      Ptch[(size_t)(row + 0) * PDIM + col] = f2bf_rn(t0);
      Ptch[(size_t)(row + 1) * PDIM + col] = f2bf_rn(t1);
      Ptch[(size_t)(row + 2) * PDIM + col] = f2bf_rn(t2);
      Ptch[(size_t)(row + 3) * PDIM + col] = f2bf_rn(t3);
      csum[j] += t0 + t1 + t2 + t3;
      #pragma unroll
      for (int g = 0; g < 6; g++){
        gp[0][g] += t0 * wgr[j][g];
        gp[1][g] += t1 * wgr[j][g];
        gp[2][g] += t2 * wgr[j][g];
        gp[3][g] += t3 * wgr[j][g];
      }
    }
    // reduce gate partials across the 16 lr lanes
    #pragma unroll
    for (int s = 1; s < 16; s <<= 1){
      #pragma unroll
      for (int k = 0; k < 4; k++)
        #pragma unroll
        for (int g = 0; g < 6; g++)
          gp[k][g] += __shfl_xor(gp[k][g], s);
    }
    if (lr == 0){
      #pragma unroll
      for (int k = 0; k < 4; k++)
        #pragma unroll
        for (int g = 0; g < 6; g++)
          atomicAdd(&glog[(size_t)(row + k) * 6 + g], gp[k][g]);
    }
  }
  // bag column sums
  #pragma unroll
  for (int j = 0; j < 4; j++){
    float s = csum[j];
    s += __shfl_xor(s, 16);
    s += __shfl_xor(s, 32);
    if (lane < 16) atomicAdd(&bagsum[n0 + wn + j * 16 + lane], s);
  }
}

// ---------------------------------------------------------------------------
// gates_small: from glog[t][6] compute router_logits out, masks, keys,
// counts, 4096-bin level-1 histograms.
// ---------------------------------------------------------------------------
__global__ void gates_small(const float* __restrict__ glog, float* __restrict__ dout,
                            unsigned int* __restrict__ wkey, unsigned char* __restrict__ mask3,
                            int* __restrict__ params, int* __restrict__ hist)
{
  __shared__ int lc[3];
  const int tid = threadIdx.x;
  if (tid < 3) lc[tid] = 0;
  __syncthreads();
  const int t = blockIdx.x * 256 + tid;
  float2 p0 = *(const float2*)(glog + (size_t)t * 6);
  float2 p1 = *(const float2*)(glog + (size_t)t * 6 + 2);
  float2 p2 = *(const float2*)(glog + (size_t)t * 6 + 4);
  dout[8 + 2 * t]     = p0.x;
  dout[8 + 2 * t + 1] = p0.y;
  int m0 = p0.y > p0.x;
  int m1 = p1.y > p1.x;
  int m2 = p2.y > p2.x;
  mask3[t] = (unsigned char)(m0 | (m1 << 1) | (m2 << 2));
  float d = fabsf(p0.x - p0.y);
  float w = 1.0f / (1.0f + __expf(-d));
  unsigned int u = __float_as_uint(w);
  u = u < 0x3F000000u ? 0x3F000000u : u;
  u = u > 0x3F7FFFFFu ? 0x3F7FFFFFu : u;
  wkey[t] = u;
  int b = (int)((u >> 11) & 0xFFFu);
  if (m0){ atomicAdd(&hist[b], 1);        atomicAdd(&lc[0], 1); }
  if (m1){ atomicAdd(&hist[4096 + b], 1); atomicAdd(&lc[1], 1); }
  if (m2){ atomicAdd(&hist[8192 + b], 1); atomicAdd(&lc[2], 1); }
  __syncthreads();
  if (tid < 3 && lc[tid]) atomicAdd(&params[tid], lc[tid]);
}

// ---------------------------------------------------------------------------
// find_bucket: nums via shifts; 12-bit bucket of nums-th largest (suffix scan)
// params: [0..2] cnt [3..5] nums [6..8] bucket [9..11] rank-in-bucket
//         [12..14] theta_u [15..17] r_ties [18..20] c_eq [21] compact count
// ---------------------------------------------------------------------------
__global__ void find_bucket(int* __restrict__ params, const int* __restrict__ hist)
{
  __shared__ int cs[256], orig[256];
  __shared__ int selc, selrk;
  const int tid = threadIdx.x;
  for (int e = 0; e < 3; e++){
    int cnt = params[e];
    int shift = (e == 1) ? 1 : 2;
    int nums = cnt >> shift;
    if (nums == 0) nums = cnt;
    if (tid == 0) params[3 + e] = nums;
    __syncthreads();
    if (nums == 0){
      if (tid == 0){ params[6 + e] = -1; params[9 + e] = 0; }
      __syncthreads();
      continue;
    }
    const int* h = hist + e * 4096 + tid * 16;
    int s = 0;
    #pragma unroll
    for (int j = 0; j < 16; j++) s += h[j];
    cs[tid] = s; orig[tid] = s;
    __syncthreads();
    for (int off = 1; off < 256; off <<= 1){
      int v = (tid + off < 256) ? cs[tid + off] : 0;
      __syncthreads();
      cs[tid] += v;
      __syncthreads();
    }
    if (cs[tid] >= nums && (cs[tid] - orig[tid]) < nums){
      selc = tid; selrk = nums - (cs[tid] - orig[tid]);
    }
    __syncthreads();
    if (tid == 0){
      int ch = selc, rk = selrk;
      const int* hh = hist + e * 4096 + ch * 16;
      int acc = 0;
      for (int j = 15; j >= 0; j--){
        int c = hh[j];
        if (acc + c >= rk){ params[6 + e] = ch * 16 + j; params[9 + e] = rk - acc; break; }
        acc += c;
      }
    }
    __syncthreads();
  }
}

// ---------------------------------------------------------------------------
// level2hist: 2048-bin histogram (mantissa bits [10:0]) within chosen bucket.
// ---------------------------------------------------------------------------
__global__ void level2hist(const int* __restrict__ params, const unsigned int* __restrict__ wkey,
                           const unsigned char* __restrict__ mask3, int* __restrict__ h2)
{
  const int e = blockIdx.y;
  const int B = params[6 + e];
  if (B < 0) return;
  const unsigned char bit = (unsigned char)(1u << e);
  const int t0 = blockIdx.x * 2048 + threadIdx.x;
  #pragma unroll
  for (int i = 0; i < 8; i++){
    int t = t0 + i * 256;
    if (mask3[t] & bit){
      unsigned int u = wkey[t];
      if ((int)((u >> 11) & 0xFFFu) == B) atomicAdd(&h2[e * 2048 + (u & 2047u)], 1);
    }
  }
}

// ---------------------------------------------------------------------------
// find_theta: exact 23-bit threshold key, ties-to-take r, tie count c_eq.
// ---------------------------------------------------------------------------
__global__ void find_theta(int* __restrict__ params, const int* __restrict__ h2)
{
  const int e = blockIdx.x;
  const int tid = threadIdx.x;
  __shared__ int cs[256], orig[256];
  __shared__ int selc;
  int B = params[6 + e], rank = params[9 + e];
  if (B < 0){
    if (tid == 0){ params[12 + e] = (int)0xFFFFFFFFu; params[15 + e] = 0; params[18 + e] = 0; }
    return;
  }
  const int* h = h2 + e * 2048 + tid * 8;
  int s = 0;
  #pragma unroll
  for (int j = 0; j < 8; j++) s += h[j];
  cs[tid] = s; orig[tid] = s;
  __syncthreads();
  for (int off = 1; off < 256; off <<= 1){
    int v = (tid + off < 256) ? cs[tid + off] : 0;
    __syncthreads();
    cs[tid] += v;
    __syncthreads();
  }
  if (cs[tid] >= rank && (cs[tid] - orig[tid]) < rank) selc = tid;
  __syncthreads();
  if (tid == 0){
    int ch = selc;
    int rk = rank - (cs[ch] - orig[ch]);
    const int* hh = h2 + e * 2048 + ch * 8;
    int acc = 0;
    for (int j = 7; j >= 0; j--){
      int c = hh[j];
      if (acc + c >= rk){
        int sub = ch * 8 + j;
        params[12 + e] = (int)(0x3F000000u | ((unsigned)B << 11) | (unsigned)sub);
        params[15 + e] = rk - acc;
        params[18 + e] = c;
        break;
      }
      acc += c;
    }
  }
}

// ---------------------------------------------------------------------------
// mark_sel: fast parallel path when all ties taken; stable scan otherwise.
// ---------------------------------------------------------------------------
__global__ void mark_sel(const int* __restrict__ params, const unsigned int* __restrict__ wkey,
                         const unsigned char* __restrict__ mask3, unsigned char* __restrict__ selb)
{
  const int e = blockIdx.y;
  const int bx = blockIdx.x;
  const int tid = threadIdx.x;
  const unsigned int theta = (unsigned int)params[12 + e];
  const int r = params[15 + e];
  const int ceq = params[18 + e];
  const unsigned char bit = (unsigned char)(1u << e);
  unsigned char* sb = selb + e * T_TOK;
  if (ceq == r){
    int t0 = bx * 2048;
    #pragma unroll
    for (int i = 0; i < 8; i++){
      int t = t0 + i * 256 + tid;
      unsigned char mk = mask3[t] & bit;
      sb[t] = (mk && wkey[t] >= theta) ? 1 : 0;
    }
  } else {
    if (bx) return;
    __shared__ int basec;
    __shared__ int wsum[4];
    if (tid == 0) basec = 0;
    __syncthreads();
    const int lane = tid & 63, w = tid >> 6;
    for (int c = 0; c < 256; c++){
      int t = c * 256 + tid;
      unsigned char mk = mask3[t] & bit;
      unsigned int u = mk ? wkey[t] : 0u;
      bool gt = mk && (u > theta);
      bool eq = mk && (u == theta);
      unsigned long long bal = __ballot(eq);
      if (lane == 0) wsum[w] = __popcll(bal);
      __syncthreads();
      int wbase = 0;
      for (int ww = 0; ww < w; ww++) wbase += wsum[ww];
      int pos = basec + wbase + __popcll(bal & ((1ull << lane) - 1ull));
      sb[t] = (gt || (eq && pos < r)) ? 1 : 0;
      __syncthreads();
      if (tid == 0) basec += wsum[0] + wsum[1] + wsum[2] + wsum[3];
      __syncthreads();
    }
  }
}

// ---------------------------------------------------------------------------
// compact: tokens with total_sel>0 + multiplicity weight; count in params[21].
// ---------------------------------------------------------------------------
__global__ void compact(const unsigned char* __restrict__ selb, int* __restrict__ cidx,
                        float* __restrict__ wgt, int* __restrict__ params)
{
  int t = blockIdx.x * 256 + threadIdx.x;
  int ts = selb[t] + selb[T_TOK + t] + selb[2 * T_TOK + t];
  int lane = threadIdx.x & 63;
  unsigned long long bal = __ballot(ts > 0);
  int base = 0;
  if (lane == 0) base = atomicAdd(&params[21], __popcll(bal));
  base = __shfl(base, 0);
  if (ts){
    int pos = base + __popcll(bal & ((1ull << lane) - 1ull));
    cidx[pos] = t;
    wgt[pos] = (float)ts;
  }
}

// ---------------------------------------------------------------------------
// meanfeat_c: column sums of (bf16) patches over sel0/sel1 rows, via the
// compacted union list.
// ---------------------------------------------------------------------------
__global__ void meanfeat_c(const unsigned short* __restrict__ Ptch,
                           const unsigned char* __restrict__ selb,
                           const int* __restrict__ cidx, const int* __restrict__ params,
                           float* __restrict__ mf)
{
  const int count = params[21];
  const int base = blockIdx.x * 256;
  if (base >= count) return;
  const int n = min(256, count - base);
  const int tid = threadIdx.x;
  __shared__ int cl[256];
  __shared__ unsigned char f0s[256], f1s[256];
  if (tid < n){
    int c = cidx[base + tid];
    cl[tid] = c;
    f0s[tid] = selb[c];
    f1s[tid] = selb[T_TOK + c];
  }
  __syncthreads();
  float s00 = 0, s01 = 0, s10 = 0, s11 = 0;
  for (int i = 0; i < n; i++){
    int f0 = f0s[i], f1 = f1s[i];
    if (f0 | f1){
      unsigned int u = *(const unsigned int*)(Ptch + (size_t)cl[i] * PDIM + tid * 2);
      float vx = bf2f((unsigned short)(u & 0xFFFFu));
      float vy = bf2f((unsigned short)(u >> 16));
      if (f0){ s00 += vx; s01 += vy; }
      if (f1){ s10 += vx; s11 += vy; }
    }
  }
  atomicAdd(&mf[tid * 2],           s00);
  atomicAdd(&mf[tid * 2 + 1],       s01);
  atomicAdd(&mf[512 + tid * 2],     s10);
  atomicAdd(&mf[512 + tid * 2 + 1], s11);
}

// ---------------------------------------------------------------------------
// gemm_agg: agg column sums = sum_rows w(row) * tanh(patches[row] @ W_a1),
// single-product bf16, rows indirected through compacted list.
// ---------------------------------------------------------------------------
__global__ __launch_bounds__(256, 4)
void gemm_agg(const unsigned short* __restrict__ Ptch,
              const unsigned short* __restrict__ Bhg,
              float* __restrict__ aggsum,
              const int* __restrict__ cidx,
              const float* __restrict__ wgt,
              const int* __restrict__ params)
{
  __shared__ __align__(16) unsigned short Ah[4096];
  __shared__ __align__(16) unsigned short Bh[4096];
  __shared__ int   cidxl[128];
  __shared__ float wl[128];

  const int tid = threadIdx.x;
  const int m0 = blockIdx.y * 128;
  const int n0 = blockIdx.x * 128;
  const int count = params[21];
  if (m0 >= count) return;
  if (tid < 128){
    int g = m0 + tid;
    if (g < count){ cidxl[tid] = cidx[g]; wl[tid] = wgt[g]; }
    else          { cidxl[tid] = 0;       wl[tid] = 0.f;   }
  }
  __syncthreads();

  const int lane = tid & 63;
  const int wv   = tid >> 6;
  const int wm   = (wv & 1) << 6;
  const int wn   = (wv >> 1) << 6;
  const int lr   = lane & 15;
  const int quad = lane >> 4;

  const int arow = tid >> 1;
  const int akh  = (tid & 1) << 4;
  const int aq0  = (tid & 1) << 1;
  const unsigned short* asrc = Ptch + (size_t)cidxl[arow] * PDIM + akh;

  floatx4 acc[4][4];
  #pragma unroll
  for (int i = 0; i < 4; i++)
    #pragma unroll
    for (int j = 0; j < 4; j++)
      acc[i][j] = (floatx4){0.f, 0.f, 0.f, 0.f};

  for (int kb = 0; kb < 16; ++kb){
    const int k0 = kb << 5;
    {
      ushortx8 h0 = *(const ushortx8*)(asrc + k0);
      ushortx8 h1 = *(const ushortx8*)(asrc + k0 + 8);
      *(ushortx8*)&Ah[lds_off(arow, aq0)]     = h0;
      *(ushortx8*)&Ah[lds_off(arow, aq0 + 1)] = h1;
    }
    #pragma unroll
    for (int it = 0; it < 2; it++){
      int lin = it * 256 + tid;
      int row = lin >> 2;
      int qb  = lin & 3;
      ushortx8 bh = *(const ushortx8*)(Bhg + (size_t)(n0 + row) * PDIM + k0 + qb * 8);
      *(ushortx8*)&Bh[lds_off(row, qb)] = bh;
    }
    __syncthreads();
    shortx8 a0[4], b0[4];
    #pragma unroll
    for (int i = 0; i < 4; i++){
      a0[i] = *(const shortx8*)&Ah[lds_off(wm + i * 16 + lr, quad)];
      b0[i] = *(const shortx8*)&Bh[lds_off(wn + i * 16 + lr, quad)];
    }
    #pragma unroll
    for (int i = 0; i < 4; i++)
      #pragma unroll
      for (int j = 0; j < 4; j++)
        acc[i][j] = __builtin_amdgcn_mfma_f32_16x16x32_bf16(a0[i], b0[j], acc[i][j], 0, 0, 0);
    __syncthreads();
  }

  float csum[4] = {0.f, 0.f, 0.f, 0.f};
  #pragma unroll
  for (int i = 0; i < 4; i++){
    const float4 wv4 = *(const float4*)&wl[wm + i * 16 + (quad << 2)];
    #pragma unroll
    for (int j = 0; j < 4; j++){
      csum[j] += ftanh(acc[i][j][0]) * wv4.x + ftanh(acc[i][j][1]) * wv4.y
               + ftanh(acc[i][j][2]) * wv4.z + ftanh(acc[i][j][3]) * wv4.w;
    }
  }
  #pragma unroll
  for (int j = 0; j < 4; j++){
    float s = csum[j];
    s += __shfl_xor(s, 16);
    s += __shfl_xor(s, 32);
    if (lane < 16) atomicAdd(&aggsum[n0 + wn + j * 16 + lane], s);
  }
}

// ---------------------------------------------------------------------------
// finalize: all small outputs.
// d_out: [0,2) e_Y_logits | [2] e_Y_hat | [3,5) Y_logits | [5,7) Y_prob |
//        [7] Y_hat | [8,131080) router_logits | [131080] joint | [131081,85) distribute
// ---------------------------------------------------------------------------
__global__ void finalize(const float* __restrict__ bagsum, const float* __restrict__ aggsum,
                         const float* __restrict__ mf, const int* __restrict__ params,
                         const float* __restrict__ Wcls1, const float* __restrict__ Wclf,
                         const float* __restrict__ Wacls, float* __restrict__ dout)
{
  const int lane = threadIdx.x;  // 64 threads
  const int nums0 = params[3], nums1 = params[4], nums2 = params[5];
  const float invT = 1.0f / 65536.0f;
  const float inv0 = 1.0f / (float)(nums0 > 0 ? nums0 : 1);
  const float inv1 = 1.0f / (float)(nums1 > 0 ? nums1 : 1);
  const float totn = (float)(nums0 + nums1 + nums2);
  const float invA = 1.0f / fmaxf(totn, 1.0f);
  float y0 = 0, y1 = 0, a0 = 0, a1 = 0;
  float l00 = 0, l01 = 0, l02 = 0, l10 = 0, l11 = 0, l12 = 0;
  #pragma unroll
  for (int j = 0; j < 8; j++){
    int p = lane * 8 + j;
    float bg = bagsum[p] * invT;
    y0 += bg * Wcls1[p * 2]; y1 += bg * Wcls1[p * 2 + 1];
    float ag = aggsum[p] * invA;
    a0 += ag * Wacls[p * 2]; a1 += ag * Wacls[p * 2 + 1];
    float m0v = mf[p] * inv0;
    l00 += m0v * Wclf[p * 3]; l01 += m0v * Wclf[p * 3 + 1]; l02 += m0v * Wclf[p * 3 + 2];
    float m1v = mf[512 + p] * inv1;
    l10 += m1v * Wclf[1536 + p * 3]; l11 += m1v * Wclf[1536 + p * 3 + 1]; l12 += m1v * Wclf[1536 + p * 3 + 2];
  }
  #pragma unroll
  for (int off = 1; off < 64; off <<= 1){
    y0 += __shfl_xor(y0, off);   y1 += __shfl_xor(y1, off);
    a0 += __shfl_xor(a0, off);   a1 += __shfl_xor(a1, off);
    l00 += __shfl_xor(l00, off); l01 += __shfl_xor(l01, off); l02 += __shfl_xor(l02, off);
    l10 += __shfl_xor(l10, off); l11 += __shfl_xor(l11, off); l12 += __shfl_xor(l12, off);
  }
  if (lane == 0){
    dout[0] = a0; dout[1] = a1;
    dout[2] = (a1 > a0) ? 1.0f : 0.0f;
    dout[3] = y0; dout[4] = y1;
    float mx = fmaxf(y0, y1), e0 = expf(y0 - mx), e1 = expf(y1 - mx), inv = 1.0f / (e0 + e1);
    dout[5] = e0 * inv; dout[6] = e1 * inv;
    dout[7] = (y1 > y0) ? 1.0f : 0.0f;
    float m3 = fmaxf(fmaxf(l00, l01), l02);
    float lse0 = m3 + logf(expf(l00 - m3) + expf(l01 - m3) + expf(l02 - m3));
    float m4 = fmaxf(fmaxf(l10, l11), l12);
    float lse1 = m4 + logf(expf(l10 - m4) + expf(l11 - m4) + expf(l12 - m4));
    dout[131080] = (lse0 - l00) + (lse1 - l11);
    dout[131081] = 65536.0f;
    dout[131082] = (float)nums0;
    dout[131083] = (float)nums1;
    dout[131084] = (float)nums2;
  }
}

// ---------------------------------------------------------------------------
extern "C" void kernel_launch(void* const* d_in, const int* in_sizes, int n_in,
                              void* d_out, int out_size, void* d_ws, size_t ws_size,
                              hipStream_t stream)
{
  const float* X      = (const float*)d_in[0];
  const float* W_t1   = (const float*)d_in[1];
  const float* W_cls1 = (const float*)d_in[2];
  const float* Wg0    = (const float*)d_in[3];
  const float* Wg1    = (const float*)d_in[4];
  const float* Wg2    = (const float*)d_in[5];
  const float* W_clf  = (const float*)d_in[6];
  const float* W_a1   = (const float*)d_in[7];
  const float* W_acls = (const float*)d_in[8];
  float* dout = (float*)d_out;
  char* ws = (char*)d_ws;

  // workspace layout (bytes)
  unsigned short* Ptch  = (unsigned short*)(ws + 0);           // 67108864
  unsigned short* W1th  = (unsigned short*)(ws + 67108864);    // 1048576
  unsigned short* W1tl  = (unsigned short*)(ws + 68157440);    // 1048576
  unsigned short* Wath  = (unsigned short*)(ws + 69206016);    // 524288
  unsigned int*   wkey  = (unsigned int*)  (ws + 69730304);    // 262144
  unsigned char*  mask3 = (unsigned char*) (ws + 69992448);    // 65536
  unsigned char*  selb  = (unsigned char*) (ws + 70057984);    // 196608
  int*            cidx  = (int*)           (ws + 70254592);    // 262144
  float*          wgt   = (float*)         (ws + 70516736);    // 262144
  int*            zbase = (int*)           (ws + 70778880);    // 413760*4 zeroed
  float* glog   = (float*)zbase;                               // 65536*6
  int*   hist   = zbase + 393216;                              // 3*4096
  int*   h2     = zbase + 405504;                              // 3*2048
  int*   params = zbase + 411648;                              // 64
  float* bagsum = (float*)(zbase + 411712);                    // 512
  float* aggsum = (float*)(zbase + 412224);                    // 512
  float* mf     = (float*)(zbase + 412736);                    // 1024 (end 413760)

  prep<<<4689, 256, 0, stream>>>(W_t1, W_a1, W1th, W1tl, Wath, zbase);

  gemm_main<<<dim3(4, 512), 256, 0, stream>>>(
      X, W1th, W1tl, Ptch, bagsum, glog, Wg0, Wg1, Wg2);

  gates_small<<<256, 256, 0, stream>>>(glog, dout, wkey, mask3, params, hist);

  find_bucket<<<1, 256, 0, stream>>>(params, hist);
  level2hist<<<dim3(32, 3), 256, 0, stream>>>(params, wkey, mask3, h2);
  find_theta<<<3, 256, 0, stream>>>(params, h2);
  mark_sel<<<dim3(32, 3), 256, 0, stream>>>(params, wkey, mask3, selb);
  compact<<<256, 256, 0, stream>>>(selb, cidx, wgt, params);

  meanfeat_c<<<256, 256, 0, stream>>>(Ptch, selb, cidx, params, mf);

  gemm_agg<<<dim3(4, 512), 256, 0, stream>>>(Ptch, Wath, aggsum, cidx, wgt, params);

  finalize<<<1, 64, 0, stream>>>(bagsum, aggsum, mf, params, W_cls1, W_clf, W_acls, dout);
}